// Round 21
// baseline (340.866 us; speedup 1.0000x reference)
//
#include <hip/hip_runtime.h>

// Fused GQA prefill: cvt4(fp32->bf16: hs,Wq,Wk,Wv) -> QKV proj (8-phase 256^2,
// V transposed epilogue; 64 extra blocks convert Wo on otherwise-idle CUs) ->
// RoPE(K only; Q roped in-register in attn) -> causal flash attn (8-wave,
// KVBLK=64 dbuf, counted vmcnt, defer-max, setprio MFMA, XCD kh-locality) ->
// O proj (m97 128^2, XCD 8x8 rectangle map).
// B=1, T=2048, HID=4096, H=32, HKV=8, DH=128, pos=0.

#define DEVI __device__ __forceinline__

typedef __attribute__((ext_vector_type(8))) short short8;
typedef __attribute__((ext_vector_type(4))) float f32x4;

DEVI unsigned short f2bf(float f) {
  union { float f; unsigned u; } x; x.f = f;
  unsigned r = x.u + 0x7FFFu + ((x.u >> 16) & 1u);
  return (unsigned short)(r >> 16);
}
DEVI float bf2f(unsigned short h) {
  union { unsigned u; float f; } x; x.u = ((unsigned)h) << 16;
  return x.f;
}
DEVI f32x4 mfma16(short8 a, short8 b, f32x4 c) {
  return __builtin_amdgcn_mfma_f32_16x16x32_bf16(a, b, c, 0, 0, 0);
}
DEVI void gl2lds16(const unsigned short* g, unsigned short* l) {
  __builtin_amdgcn_global_load_lds(
      (const __attribute__((address_space(1))) unsigned int*)g,
      (__attribute__((address_space(3))) unsigned int*)l, 16, 0, 0);
}
DEVI void bar() { __builtin_amdgcn_s_barrier(); }
DEVI void sfence() { __builtin_amdgcn_sched_barrier(0); }

DEVI void cvt_region(const float* __restrict__ src,
                     unsigned short* __restrict__ dst, int n4, int start,
                     int stride) {
  for (int i = start; i < n4; i += stride) {
    float4 v = ((const float4*)src)[i];
    ushort4 h;
    h.x = f2bf(v.x); h.y = f2bf(v.y); h.z = f2bf(v.z); h.w = f2bf(v.w);
    ((ushort4*)dst)[i] = h;
  }
}

// ---------------------------------------------------------------------------
// One-launch fp32 -> bf16 conversion of hs, Wq, Wk, Wv (Wo handled in qkv).
// ---------------------------------------------------------------------------
__global__ __launch_bounds__(256)
void cvt4_kernel(const float* __restrict__ s0, const float* __restrict__ s1,
                 const float* __restrict__ s2, const float* __restrict__ s3,
                 unsigned short* __restrict__ d0, unsigned short* __restrict__ d1,
                 unsigned short* __restrict__ d2, unsigned short* __restrict__ d3,
                 int n0, int n1, int n2, int n3) {
  const int start = blockIdx.x * 256 + threadIdx.x;
  const int stride = gridDim.x * 256;
  cvt_region(s0, d0, n0, start, stride);
  cvt_region(s1, d1, n1, start, stride);
  cvt_region(s2, d2, n2, start, stride);
  cvt_region(s3, d3, n3, start, stride);
}

// ---------------------------------------------------------------------------
// GEMM 1: QKV projection, 8-phase 256x256 template, 1D grid of 256 blocks:
// bid<192 = GEMM (bx=bid%24, by=bid/24); bid>=192 = 64 converter blocks that
// stream Wo fp32->bf16 on the CUs the GEMM leaves idle. V-region GEMM blocks
// write output TRANSPOSED into VtG.
// ---------------------------------------------------------------------------
__global__ __launch_bounds__(512, 2)
void gemm_qkv_8ph(const unsigned short* __restrict__ hsb,
                  const unsigned short* __restrict__ Wqb,
                  const unsigned short* __restrict__ Wkb,
                  const unsigned short* __restrict__ Wvb,
                  unsigned short* __restrict__ Qb,
                  unsigned short* __restrict__ Kb,
                  unsigned short* __restrict__ VtG,
                  const float* __restrict__ Wo,
                  unsigned short* __restrict__ Wob) {
  const int K = 4096;
  const int NT = 64;
  __shared__ __align__(16) unsigned short Ls[2][2][2][256][32]; // 128 KiB
  const int tid = threadIdx.x, lane = tid & 63, w = tid >> 6;
  const int bid = blockIdx.x;

  if (bid >= 192) {
    const int start = (bid - 192) * 512 + tid;
    cvt_region(Wo, Wob, 4 * 1024 * 1024, start, 64 * 512);
    return;
  }

  const int wr = w >> 2, wc = w & 3;
  const int m0 = (bid / 24) * 256;
  const int n0g = (bid % 24) * 256;

  const unsigned short* Bsrc; unsigned short* outp; int ldo, oc; bool isv = false;
  if (n0g < 4096)      { Bsrc = Wqb + (size_t)n0g * K;          outp = Qb; ldo = 4096; oc = n0g; }
  else if (n0g < 5120) { Bsrc = Wkb + (size_t)(n0g - 4096) * K; outp = Kb; ldo = 1024; oc = n0g - 4096; }
  else                 { Bsrc = Wvb + (size_t)(n0g - 5120) * K; outp = VtG; ldo = 0; oc = n0g - 5120; isv = true; }
  const unsigned short* Asrc = hsb + (size_t)m0 * K;

  auto stageU = [&](const unsigned short* src, int ab, int kh, int tt, int bb) {
#pragma unroll
    for (int j = 0; j < 2; ++j) {
      const int seg = j * 8 + w;
      const int row = seg * 16 + (lane >> 2);
      const int cs  = (lane & 3) ^ ((row >> 1) & 3);
      gl2lds16(src + (size_t)row * K + tt * 64 + kh * 32 + cs * 8,
               &Ls[bb][ab][kh][seg * 16][0]);
    }
  };
  auto ldA = [&](int bb, int kh, int fm) -> short8 {
    const int ra = wr * 128 + fm * 16 + (lane & 15);
    const int cs = (lane >> 4) ^ ((ra >> 1) & 3);
    return *(const short8*)&Ls[bb][0][kh][ra][cs * 8];
  };
  auto ldB = [&](int bb, int kh, int fn) -> short8 {
    const int rb = wc * 64 + fn * 16 + (lane & 15);
    const int cs = (lane >> 4) ^ ((rb >> 1) & 3);
    return *(const short8*)&Ls[bb][1][kh][rb][cs * 8];
  };

  f32x4 acc[8][4];
#pragma unroll
  for (int i = 0; i < 8; ++i)
#pragma unroll
    for (int j = 0; j < 4; ++j) acc[i][j] = (f32x4){0.f, 0.f, 0.f, 0.f};

  stageU(Asrc, 0, 0, 0, 0);
  stageU(Asrc, 0, 1, 0, 0);
  stageU(Bsrc, 1, 0, 0, 0);
  stageU(Bsrc, 1, 1, 0, 0);
  stageU(Bsrc, 1, 0, 1, 1);
  stageU(Asrc, 0, 0, 1, 1);
  stageU(Bsrc, 1, 1, 1, 1);
  asm volatile("s_waitcnt vmcnt(6)" ::: "memory");
  bar();
  sfence();

  short8 af[4], bfr[4];
  for (int t = 0; t < NT; ++t) {
    const int bb = t & 1, nb = bb ^ 1;
    // P1: (kh0, mq0); stage A(t+1)-kh1 -> nb
#pragma unroll
    for (int i = 0; i < 4; ++i) af[i] = ldA(bb, 0, i);
#pragma unroll
    for (int i = 0; i < 4; ++i) bfr[i] = ldB(bb, 0, i);
    if (t + 1 < NT) stageU(Asrc, 0, 1, t + 1, nb);
    bar();
    __builtin_amdgcn_s_setprio(1);
#pragma unroll
    for (int i = 0; i < 4; ++i)
#pragma unroll
      for (int j = 0; j < 4; ++j) acc[i][j] = mfma16(af[i], bfr[j], acc[i][j]);
    __builtin_amdgcn_s_setprio(0);
    sfence(); bar(); sfence();
    // P2: (kh0, mq1); stage B(t+2)-kh0 -> bb
#pragma unroll
    for (int i = 0; i < 4; ++i) af[i] = ldA(bb, 0, 4 + i);
    if (t + 2 < NT) stageU(Bsrc, 1, 0, t + 2, bb);
    bar();
    __builtin_amdgcn_s_setprio(1);
#pragma unroll
    for (int i = 0; i < 4; ++i)
#pragma unroll
      for (int j = 0; j < 4; ++j) acc[4 + i][j] = mfma16(af[i], bfr[j], acc[4 + i][j]);
    __builtin_amdgcn_s_setprio(0);
    sfence(); bar(); sfence();
    // P3: (kh1, mq0); stage A(t+2)-kh0 -> bb
#pragma unroll
    for (int i = 0; i < 4; ++i) af[i] = ldA(bb, 1, i);
#pragma unroll
    for (int i = 0; i < 4; ++i) bfr[i] = ldB(bb, 1, i);
    if (t + 2 < NT) stageU(Asrc, 0, 0, t + 2, bb);
    bar();
    __builtin_amdgcn_s_setprio(1);
#pragma unroll
    for (int i = 0; i < 4; ++i)
#pragma unroll
      for (int j = 0; j < 4; ++j) acc[i][j] = mfma16(af[i], bfr[j], acc[i][j]);
    __builtin_amdgcn_s_setprio(0);
    sfence(); bar(); sfence();
    // P4: (kh1, mq1); stage B(t+2)-kh1 -> bb; counted vmcnt
#pragma unroll
    for (int i = 0; i < 4; ++i) af[i] = ldA(bb, 1, 4 + i);
    if (t + 2 < NT) stageU(Bsrc, 1, 1, t + 2, bb);
    bar();
    __builtin_amdgcn_s_setprio(1);
#pragma unroll
    for (int i = 0; i < 4; ++i)
#pragma unroll
      for (int j = 0; j < 4; ++j) acc[4 + i][j] = mfma16(af[i], bfr[j], acc[4 + i][j]);
    __builtin_amdgcn_s_setprio(0);
    if (t < NT - 2) asm volatile("s_waitcnt vmcnt(6)" ::: "memory");
    else            asm volatile("s_waitcnt vmcnt(0)" ::: "memory");
    sfence(); bar(); sfence();
  }

  if (isv) {
#pragma unroll
    for (int fm = 0; fm < 8; ++fm) {
      const int rb0 = m0 + wr * 128 + fm * 16 + ((lane >> 4) << 2);
#pragma unroll
      for (int fn = 0; fn < 4; ++fn) {
        const int cb = oc + wc * 64 + fn * 16 + (lane & 15);
        ushort4 v;
        v.x = f2bf(acc[fm][fn][0]); v.y = f2bf(acc[fm][fn][1]);
        v.z = f2bf(acc[fm][fn][2]); v.w = f2bf(acc[fm][fn][3]);
        *(ushort4*)(VtG + (size_t)cb * 2048 + rb0) = v;
      }
    }
  } else {
#pragma unroll
    for (int fm = 0; fm < 8; ++fm) {
      const int rb0 = m0 + wr * 128 + fm * 16 + ((lane >> 4) << 2);
#pragma unroll
      for (int fn = 0; fn < 4; ++fn) {
        const int cb = oc + wc * 64 + fn * 16 + (lane & 15);
#pragma unroll
        for (int r = 0; r < 4; ++r)
          outp[(size_t)(rb0 + r) * ldo + cb] = f2bf(acc[fm][fn][r]);
      }
    }
  }
}

// ---------------------------------------------------------------------------
// RoPE in place on bf16 K only (Q is roped in-register inside attn).
// ---------------------------------------------------------------------------
__global__ __launch_bounds__(256)
void rope_k_kernel(unsigned short* __restrict__ Kb,
                   const int* __restrict__ posp) {
  const int KP = 2048 * 8 * 64;
  int idx = blockIdx.x * 256 + threadIdx.x;
  if (idx >= KP) return;
  int t = idx >> 9; int rem = idx & 511; int hh = rem >> 6; int d = rem & 63;
  float freq = exp2f(-(float)d * 0.29580575880077f);  // 500000^(-2d/128)
  float ang = (float)(t + posp[0]) * freq;
  float s, c;
  __sincosf(ang, &s, &c);
  size_t i1 = (size_t)t * 1024 + hh * 128 + d;
  float x1 = bf2f(Kb[i1]), x2 = bf2f(Kb[i1 + 64]);
  Kb[i1]      = f2bf(x1 * c - x2 * s);
  Kb[i1 + 64] = f2bf(x1 * s + x2 * c);
}

// ---------------------------------------------------------------------------
// Causal GQA flash attention. 512 thr = 8 waves x 16 q-rows, KVBLK=64,
// double-buffered counted-vmcnt staging, defer-max (T13, THR=8), setprio
// around MFMA clusters (T5), XCD kh-locality map, in-register Q-RoPE.
// ---------------------------------------------------------------------------
__global__ __launch_bounds__(512)
void attn_kernel(const unsigned short* __restrict__ Qb,
                 const unsigned short* __restrict__ Kb,
                 const unsigned short* __restrict__ VtG,
                 unsigned short* __restrict__ Ob,
                 const int* __restrict__ posp) {
  __shared__ __align__(16) unsigned short Ks[2][64][128];
  __shared__ __align__(16) unsigned short Vt[2][128][64];
  __shared__ __align__(16) unsigned short Ps[8][16][64];
  const int tid = threadIdx.x, lane = tid & 63, w = tid >> 6;
  const int b = blockIdx.x;
  const int kh = b & 7;
  const int h  = kh * 4 + ((b >> 3) & 3);
  const int qi = b >> 5;
  const int qt = (qi < 8) ? qi : 23 - qi;
  const int q0 = qt * 128;
  const float SCALE = 0.08838834764831845f;

  const int qrow = q0 + w * 16 + (lane & 15);
  short8 aq[4];
#pragma unroll
  for (int ks = 0; ks < 4; ++ks)
    aq[ks] = *(const short8*)(Qb + (size_t)qrow * 4096 + h * 128 + ks * 32 +
                              ((lane >> 4) << 3));
  // In-register RoPE on Q: pair (d, d+64) = (aq[kp][j], aq[kp+2][j]).
  {
    const float tpos = (float)(qrow + posp[0]);
#pragma unroll
    for (int kp = 0; kp < 2; ++kp)
#pragma unroll
      for (int j = 0; j < 8; ++j) {
        const int d = kp * 32 + ((lane >> 4) << 3) + j;
        float fr = exp2f(-(float)d * 0.29580575880077f);
        float ang = tpos * fr, s, c;
        __sincosf(ang, &s, &c);
        float x0 = bf2f((unsigned short)aq[kp][j]);
        float x1 = bf2f((unsigned short)aq[kp + 2][j]);
        aq[kp][j]     = (short)f2bf(x0 * c - x1 * s);
        aq[kp + 2][j] = (short)f2bf(x0 * s + x1 * c);
      }
  }

  f32x4 o_acc[8];
#pragma unroll
  for (int n8 = 0; n8 < 8; ++n8) o_acc[n8] = (f32x4){0.f, 0.f, 0.f, 0.f};
  float mst[4], lst[4];
#pragma unroll
  for (int r = 0; r < 4; ++r) { mst[r] = -1e30f; lst[r] = 0.f; }

  auto stage = [&](int st, int bb) {
    const int s0 = st * 64;
#pragma unroll
    for (int j = 0; j < 2; ++j) {
      int sr = w * 8 + j * 4 + (lane >> 4);
      int sc = (((lane & 15) << 4) ^ ((sr & 7) << 4)) >> 1;
      gl2lds16(Kb + (size_t)(s0 + sr) * 1024 + kh * 128 + sc,
               &Ks[bb][w * 8 + j * 4][0]);
    }
#pragma unroll
    for (int j = 0; j < 2; ++j) {
      int dr = w * 16 + j * 8 + (lane >> 3);
      int sc = (((lane & 7) << 4) ^ ((dr & 7) << 4)) >> 1;
      gl2lds16(VtG + (size_t)(kh * 128 + dr) * 2048 + s0 + sc,
               &Vt[bb][w * 16 + j * 8][0]);
    }
  };

  const int ntiles = 2 * (qt + 1);
  stage(0, 0);
  for (int st = 0; st < ntiles; ++st) {
    const int cb = st & 1;
    const int s0 = st * 64;
    if (st + 1 < ntiles) {
      stage(st + 1, cb ^ 1);
      asm volatile("s_waitcnt vmcnt(4)" ::: "memory");
    } else {
      asm volatile("s_waitcnt vmcnt(0)" ::: "memory");
    }
    bar(); sfence();

    f32x4 sacc[4];
#pragma unroll
    for (int ni = 0; ni < 4; ++ni) sacc[ni] = (f32x4){0.f, 0.f, 0.f, 0.f};
    __builtin_amdgcn_s_setprio(1);
#pragma unroll
    for (int ks = 0; ks < 4; ++ks) {
      const int co = ks * 64 + ((lane >> 4) << 4);
      short8 bk[4];
#pragma unroll
      for (int ni = 0; ni < 4; ++ni) {
        int kr = ni * 16 + (lane & 15);
        bk[ni] = *(const short8*)((const char*)(&Ks[cb][kr][0]) + (co ^ ((kr & 7) << 4)));
      }
#pragma unroll
      for (int ni = 0; ni < 4; ++ni)
        sacc[ni] = mfma16(aq[ks], bk[ni], sacc[ni]);
    }
    __builtin_amdgcn_s_setprio(0);

    char* pb = (char*)(&Ps[w][0][0]);
#pragma unroll
    for (int r = 0; r < 4; ++r) {
      const int qr2 = q0 + w * 16 + ((lane >> 4) << 2) + r;
      float v4[4]; float vmax = -1e30f;
#pragma unroll
      for (int ni = 0; ni < 4; ++ni) {
        int scol = s0 + ni * 16 + (lane & 15);
        float x = sacc[ni][r] * SCALE;
        if (scol > qr2) x = -1e30f;
        v4[ni] = x; vmax = fmaxf(vmax, x);
      }
      vmax = fmaxf(vmax, __shfl_xor(vmax, 1));
      vmax = fmaxf(vmax, __shfl_xor(vmax, 2));
      vmax = fmaxf(vmax, __shfl_xor(vmax, 4));
      vmax = fmaxf(vmax, __shfl_xor(vmax, 8));
      float mo = mst[r];
      if (!__all(vmax <= mo + 8.0f)) {
        float mn = fmaxf(mo, vmax);
        float al = __expf(mo - mn);
        lst[r] *= al;
#pragma unroll
        for (int n8 = 0; n8 < 8; ++n8) o_acc[n8][r] *= al;
        mst[r] = mn;
      }
      float m_use = mst[r];
      float rs = 0.f;
      const int prow = ((lane >> 4) << 2) + r;
      const int pswz = ((prow >> 2) & 3) << 5;
#pragma unroll
      for (int ni = 0; ni < 4; ++ni) {
        float p = __expf(v4[ni] - m_use);
        rs += p;
        int cbyte = (ni * 16 + (lane & 15)) * 2;
        *(unsigned short*)(pb + prow * 128 + (cbyte ^ pswz)) = f2bf(p);
      }
      rs += __shfl_xor(rs, 1);
      rs += __shfl_xor(rs, 2);
      rs += __shfl_xor(rs, 4);
      rs += __shfl_xor(rs, 8);
      lst[r] += rs;
    }

    __builtin_amdgcn_s_setprio(1);
#pragma unroll
    for (int ks2 = 0; ks2 < 2; ++ks2) {
      const int co = ks2 * 64 + ((lane >> 4) << 4);
      const int pr = lane & 15;
      short8 pa = *(const short8*)(pb + pr * 128 + (co ^ (((pr >> 2) & 3) << 5)));
#pragma unroll
      for (int n8 = 0; n8 < 8; ++n8) {
        int vr = n8 * 16 + (lane & 15);
        short8 bv = *(const short8*)((const char*)(&Vt[cb][vr][0]) + (co ^ ((vr & 7) << 4)));
        o_acc[n8] = mfma16(pa, bv, o_acc[n8]);
      }
    }
    __builtin_amdgcn_s_setprio(0);
    sfence(); bar(); sfence();
  }

#pragma unroll
  for (int r = 0; r < 4; ++r) {
    float inv = 1.0f / lst[r];
    int row = q0 + w * 16 + ((lane >> 4) << 2) + r;
#pragma unroll
    for (int n8 = 0; n8 < 8; ++n8)
      Ob[(size_t)row * 4096 + h * 128 + n8 * 16 + (lane & 15)] =
          f2bf(o_acc[n8][r] * inv);
  }
}

// ---------------------------------------------------------------------------
// GEMM 2 (m97 structure): O projection, fp32 out. XCD 8x8 rectangle map.
// ---------------------------------------------------------------------------
__global__ __launch_bounds__(256, 2)
void gemm_out_bf16(const unsigned short* __restrict__ Ab,
                   const unsigned short* __restrict__ Wob,
                   float* __restrict__ Cout) {
  const int K = 4096;
  __shared__ __align__(16) unsigned short As[128][64];
  __shared__ __align__(16) unsigned short Bs[128][64];
  const int tid = threadIdx.x, lane = tid & 63, wid = tid >> 6;
  const int bid = blockIdx.x;                 // 0..511
  const int xcd = bid & 7, idx = bid >> 3;    // idx 0..63
  const int m0 = ((xcd & 1) * 8 + (idx & 7)) * 128;
  const int n0 = ((xcd >> 1) * 8 + (idx >> 3)) * 128;
  const unsigned short* Asrc = Ab + (size_t)m0 * K;
  const unsigned short* Bsrc = Wob + (size_t)n0 * K;

  f32x4 acc[4][4];
#pragma unroll
  for (int i = 0; i < 4; ++i)
#pragma unroll
    for (int j = 0; j < 4; ++j) acc[i][j] = (f32x4){0.f, 0.f, 0.f, 0.f};

  const int wm = (wid >> 1) * 64, wn = (wid & 1) * 64;
  const int srow = wid * 32 + (lane >> 3);
  const int scol = (lane & 7) * 8;

  for (int k0 = 0; k0 < K; k0 += 64) {
#pragma unroll
    for (int i = 0; i < 4; ++i) {
      gl2lds16(Asrc + (size_t)(srow + i * 8) * K + k0 + scol, &As[wid * 32 + i * 8][0]);
      gl2lds16(Bsrc + (size_t)(srow + i * 8) * K + k0 + scol, &Bs[wid * 32 + i * 8][0]);
    }
    __syncthreads();
#pragma unroll
    for (int ks = 0; ks < 2; ++ks) {
      short8 af[4], bfr[4];
      const int co = ks * 64 + ((lane >> 4) << 4);
#pragma unroll
      for (int i = 0; i < 4; ++i) {
        af[i]  = *(const short8*)((const char*)(&As[wm + i * 16 + (lane & 15)][0]) + co);
        bfr[i] = *(const short8*)((const char*)(&Bs[wn + i * 16 + (lane & 15)][0]) + co);
      }
#pragma unroll
      for (int i = 0; i < 4; ++i)
#pragma unroll
        for (int j = 0; j < 4; ++j)
          acc[i][j] = mfma16(af[i], bfr[j], acc[i][j]);
    }
    __syncthreads();
  }

#pragma unroll
  for (int i = 0; i < 4; ++i) {
    int rb = m0 + wm + i * 16 + ((lane >> 4) << 2);
#pragma unroll
    for (int j = 0; j < 4; ++j) {
      int cb = n0 + wn + j * 16 + (lane & 15);
#pragma unroll
      for (int r = 0; r < 4; ++r)
        Cout[(size_t)(rb + r) * 4096 + cb] = acc[i][j][r];
    }
  }
}

extern "C" void kernel_launch(void* const* d_in, const int* in_sizes, int n_in,
                              void* d_out, int out_size, void* d_ws, size_t ws_size,
                              hipStream_t stream) {
  const float* hs = (const float*)d_in[0];
  const float* Wq = (const float*)d_in[1];
  const float* Wk = (const float*)d_in[2];
  const float* Wv = (const float*)d_in[3];
  const float* Wo = (const float*)d_in[4];
  const int* pos = (const int*)d_in[7];

  unsigned short* hsb = (unsigned short*)d_ws;              // 8M
  unsigned short* Wqb = hsb + (size_t)8  * 1024 * 1024;     // 16M
  unsigned short* Wkb = Wqb + (size_t)16 * 1024 * 1024;     // 4M
  unsigned short* Wvb = Wkb + (size_t)4  * 1024 * 1024;     // 4M
  unsigned short* Wob = Wvb + (size_t)4  * 1024 * 1024;     // 16M
  unsigned short* Qb  = Wob + (size_t)16 * 1024 * 1024;     // 8M
  unsigned short* Kb  = Qb  + (size_t)8  * 1024 * 1024;     // 2M
  unsigned short* VtG = Kb  + (size_t)2  * 1024 * 1024;     // 2M
  unsigned short* Ob  = VtG + (size_t)2  * 1024 * 1024;     // 8M
  float* out = (float*)d_out;

  cvt4_kernel<<<dim3(2048), 256, 0, stream>>>(
      hs, Wq, Wk, Wv, hsb, Wqb, Wkb, Wvb,
      2 * 1024 * 1024, 4 * 1024 * 1024, 1 * 1024 * 1024, 1 * 1024 * 1024);

  gemm_qkv_8ph<<<dim3(256), 512, 0, stream>>>(hsb, Wqb, Wkb, Wvb, Qb, Kb, VtG,
                                              Wo, Wob);

  const int kpairs = 2048 * 8 * 64;
  rope_k_kernel<<<dim3((kpairs + 255) / 256), 256, 0, stream>>>(Kb, pos);

  attn_kernel<<<dim3(512), 512, 0, stream>>>(Qb, Kb, VtG, Ob, pos);
  gemm_out_bf16<<<dim3(512), 256, 0, stream>>>(Ob, Wob, out);
}

// Round 22
// 337.971 us; speedup vs baseline: 1.0086x; 1.0086x over previous
//
#include <hip/hip_runtime.h>

// Fused GQA prefill: cvt4(fp32->bf16: hs,Wq,Wk,Wv) -> QKV proj (8-phase 256^2,
// V transposed epilogue; 64 extra blocks convert Wo on otherwise-idle CUs) ->
// RoPE(K only; Q roped in-register in attn) -> causal flash attn (8-wave,
// KVBLK=64 dbuf, counted vmcnt, defer-max, XCD kh-locality) -> O proj (m97
// 128^2, XCD 8x8 rectangle map).  B=1, T=2048, HID=4096, H=32, HKV=8, DH=128.

#define DEVI __device__ __forceinline__

typedef __attribute__((ext_vector_type(8))) short short8;
typedef __attribute__((ext_vector_type(4))) float f32x4;

DEVI unsigned short f2bf(float f) {
  union { float f; unsigned u; } x; x.f = f;
  unsigned r = x.u + 0x7FFFu + ((x.u >> 16) & 1u);
  return (unsigned short)(r >> 16);
}
DEVI float bf2f(unsigned short h) {
  union { unsigned u; float f; } x; x.u = ((unsigned)h) << 16;
  return x.f;
}
DEVI f32x4 mfma16(short8 a, short8 b, f32x4 c) {
  return __builtin_amdgcn_mfma_f32_16x16x32_bf16(a, b, c, 0, 0, 0);
}
DEVI void gl2lds16(const unsigned short* g, unsigned short* l) {
  __builtin_amdgcn_global_load_lds(
      (const __attribute__((address_space(1))) unsigned int*)g,
      (__attribute__((address_space(3))) unsigned int*)l, 16, 0, 0);
}
DEVI void bar() { __builtin_amdgcn_s_barrier(); }
DEVI void sfence() { __builtin_amdgcn_sched_barrier(0); }

DEVI void cvt_region(const float* __restrict__ src,
                     unsigned short* __restrict__ dst, int n4, int start,
                     int stride) {
  for (int i = start; i < n4; i += stride) {
    float4 v = ((const float4*)src)[i];
    ushort4 h;
    h.x = f2bf(v.x); h.y = f2bf(v.y); h.z = f2bf(v.z); h.w = f2bf(v.w);
    ((ushort4*)dst)[i] = h;
  }
}

// ---------------------------------------------------------------------------
// One-launch fp32 -> bf16 conversion of hs, Wq, Wk, Wv (Wo handled in qkv).
// ---------------------------------------------------------------------------
__global__ __launch_bounds__(256)
void cvt4_kernel(const float* __restrict__ s0, const float* __restrict__ s1,
                 const float* __restrict__ s2, const float* __restrict__ s3,
                 unsigned short* __restrict__ d0, unsigned short* __restrict__ d1,
                 unsigned short* __restrict__ d2, unsigned short* __restrict__ d3,
                 int n0, int n1, int n2, int n3) {
  const int start = blockIdx.x * 256 + threadIdx.x;
  const int stride = gridDim.x * 256;
  cvt_region(s0, d0, n0, start, stride);
  cvt_region(s1, d1, n1, start, stride);
  cvt_region(s2, d2, n2, start, stride);
  cvt_region(s3, d3, n3, start, stride);
}

// ---------------------------------------------------------------------------
// GEMM 1: QKV projection, 8-phase 256x256 template, 1D grid of 256 blocks:
// bid<192 = GEMM (bx=bid%24, by=bid/24); bid>=192 = 64 converter blocks that
// stream Wo fp32->bf16 on the CUs the GEMM leaves idle. V-region GEMM blocks
// write output TRANSPOSED into VtG.
// ---------------------------------------------------------------------------
__global__ __launch_bounds__(512, 2)
void gemm_qkv_8ph(const unsigned short* __restrict__ hsb,
                  const unsigned short* __restrict__ Wqb,
                  const unsigned short* __restrict__ Wkb,
                  const unsigned short* __restrict__ Wvb,
                  unsigned short* __restrict__ Qb,
                  unsigned short* __restrict__ Kb,
                  unsigned short* __restrict__ VtG,
                  const float* __restrict__ Wo,
                  unsigned short* __restrict__ Wob) {
  const int K = 4096;
  const int NT = 64;
  __shared__ __align__(16) unsigned short Ls[2][2][2][256][32]; // 128 KiB
  const int tid = threadIdx.x, lane = tid & 63, w = tid >> 6;
  const int bid = blockIdx.x;

  if (bid >= 192) {
    const int start = (bid - 192) * 512 + tid;
    cvt_region(Wo, Wob, 4 * 1024 * 1024, start, 64 * 512);
    return;
  }

  const int wr = w >> 2, wc = w & 3;
  const int m0 = (bid / 24) * 256;
  const int n0g = (bid % 24) * 256;

  const unsigned short* Bsrc; unsigned short* outp; int ldo, oc; bool isv = false;
  if (n0g < 4096)      { Bsrc = Wqb + (size_t)n0g * K;          outp = Qb; ldo = 4096; oc = n0g; }
  else if (n0g < 5120) { Bsrc = Wkb + (size_t)(n0g - 4096) * K; outp = Kb; ldo = 1024; oc = n0g - 4096; }
  else                 { Bsrc = Wvb + (size_t)(n0g - 5120) * K; outp = VtG; ldo = 0; oc = n0g - 5120; isv = true; }
  const unsigned short* Asrc = hsb + (size_t)m0 * K;

  auto stageU = [&](const unsigned short* src, int ab, int kh, int tt, int bb) {
#pragma unroll
    for (int j = 0; j < 2; ++j) {
      const int seg = j * 8 + w;
      const int row = seg * 16 + (lane >> 2);
      const int cs  = (lane & 3) ^ ((row >> 1) & 3);
      gl2lds16(src + (size_t)row * K + tt * 64 + kh * 32 + cs * 8,
               &Ls[bb][ab][kh][seg * 16][0]);
    }
  };
  auto ldA = [&](int bb, int kh, int fm) -> short8 {
    const int ra = wr * 128 + fm * 16 + (lane & 15);
    const int cs = (lane >> 4) ^ ((ra >> 1) & 3);
    return *(const short8*)&Ls[bb][0][kh][ra][cs * 8];
  };
  auto ldB = [&](int bb, int kh, int fn) -> short8 {
    const int rb = wc * 64 + fn * 16 + (lane & 15);
    const int cs = (lane >> 4) ^ ((rb >> 1) & 3);
    return *(const short8*)&Ls[bb][1][kh][rb][cs * 8];
  };

  f32x4 acc[8][4];
#pragma unroll
  for (int i = 0; i < 8; ++i)
#pragma unroll
    for (int j = 0; j < 4; ++j) acc[i][j] = (f32x4){0.f, 0.f, 0.f, 0.f};

  stageU(Asrc, 0, 0, 0, 0);
  stageU(Asrc, 0, 1, 0, 0);
  stageU(Bsrc, 1, 0, 0, 0);
  stageU(Bsrc, 1, 1, 0, 0);
  stageU(Bsrc, 1, 0, 1, 1);
  stageU(Asrc, 0, 0, 1, 1);
  stageU(Bsrc, 1, 1, 1, 1);
  asm volatile("s_waitcnt vmcnt(6)" ::: "memory");
  bar();
  sfence();

  short8 af[4], bfr[4];
  for (int t = 0; t < NT; ++t) {
    const int bb = t & 1, nb = bb ^ 1;
    // P1: (kh0, mq0); stage A(t+1)-kh1 -> nb
#pragma unroll
    for (int i = 0; i < 4; ++i) af[i] = ldA(bb, 0, i);
#pragma unroll
    for (int i = 0; i < 4; ++i) bfr[i] = ldB(bb, 0, i);
    if (t + 1 < NT) stageU(Asrc, 0, 1, t + 1, nb);
    bar();
    __builtin_amdgcn_s_setprio(1);
#pragma unroll
    for (int i = 0; i < 4; ++i)
#pragma unroll
      for (int j = 0; j < 4; ++j) acc[i][j] = mfma16(af[i], bfr[j], acc[i][j]);
    __builtin_amdgcn_s_setprio(0);
    sfence(); bar(); sfence();
    // P2: (kh0, mq1); stage B(t+2)-kh0 -> bb
#pragma unroll
    for (int i = 0; i < 4; ++i) af[i] = ldA(bb, 0, 4 + i);
    if (t + 2 < NT) stageU(Bsrc, 1, 0, t + 2, bb);
    bar();
    __builtin_amdgcn_s_setprio(1);
#pragma unroll
    for (int i = 0; i < 4; ++i)
#pragma unroll
      for (int j = 0; j < 4; ++j) acc[4 + i][j] = mfma16(af[i], bfr[j], acc[4 + i][j]);
    __builtin_amdgcn_s_setprio(0);
    sfence(); bar(); sfence();
    // P3: (kh1, mq0); stage A(t+2)-kh0 -> bb
#pragma unroll
    for (int i = 0; i < 4; ++i) af[i] = ldA(bb, 1, i);
#pragma unroll
    for (int i = 0; i < 4; ++i) bfr[i] = ldB(bb, 1, i);
    if (t + 2 < NT) stageU(Asrc, 0, 0, t + 2, bb);
    bar();
    __builtin_amdgcn_s_setprio(1);
#pragma unroll
    for (int i = 0; i < 4; ++i)
#pragma unroll
      for (int j = 0; j < 4; ++j) acc[i][j] = mfma16(af[i], bfr[j], acc[i][j]);
    __builtin_amdgcn_s_setprio(0);
    sfence(); bar(); sfence();
    // P4: (kh1, mq1); stage B(t+2)-kh1 -> bb; counted vmcnt
#pragma unroll
    for (int i = 0; i < 4; ++i) af[i] = ldA(bb, 1, 4 + i);
    if (t + 2 < NT) stageU(Bsrc, 1, 1, t + 2, bb);
    bar();
    __builtin_amdgcn_s_setprio(1);
#pragma unroll
    for (int i = 0; i < 4; ++i)
#pragma unroll
      for (int j = 0; j < 4; ++j) acc[4 + i][j] = mfma16(af[i], bfr[j], acc[4 + i][j]);
    __builtin_amdgcn_s_setprio(0);
    if (t < NT - 2) asm volatile("s_waitcnt vmcnt(6)" ::: "memory");
    else            asm volatile("s_waitcnt vmcnt(0)" ::: "memory");
    sfence(); bar(); sfence();
  }

  if (isv) {
#pragma unroll
    for (int fm = 0; fm < 8; ++fm) {
      const int rb0 = m0 + wr * 128 + fm * 16 + ((lane >> 4) << 2);
#pragma unroll
      for (int fn = 0; fn < 4; ++fn) {
        const int cb = oc + wc * 64 + fn * 16 + (lane & 15);
        ushort4 v;
        v.x = f2bf(acc[fm][fn][0]); v.y = f2bf(acc[fm][fn][1]);
        v.z = f2bf(acc[fm][fn][2]); v.w = f2bf(acc[fm][fn][3]);
        *(ushort4*)(VtG + (size_t)cb * 2048 + rb0) = v;
      }
    }
  } else {
#pragma unroll
    for (int fm = 0; fm < 8; ++fm) {
      const int rb0 = m0 + wr * 128 + fm * 16 + ((lane >> 4) << 2);
#pragma unroll
      for (int fn = 0; fn < 4; ++fn) {
        const int cb = oc + wc * 64 + fn * 16 + (lane & 15);
#pragma unroll
        for (int r = 0; r < 4; ++r)
          outp[(size_t)(rb0 + r) * ldo + cb] = f2bf(acc[fm][fn][r]);
      }
    }
  }
}

// ---------------------------------------------------------------------------
// RoPE in place on bf16 K only (Q is roped in-register inside attn).
// ---------------------------------------------------------------------------
__global__ __launch_bounds__(256)
void rope_k_kernel(unsigned short* __restrict__ Kb,
                   const int* __restrict__ posp) {
  const int KP = 2048 * 8 * 64;
  int idx = blockIdx.x * 256 + threadIdx.x;
  if (idx >= KP) return;
  int t = idx >> 9; int rem = idx & 511; int hh = rem >> 6; int d = rem & 63;
  float freq = exp2f(-(float)d * 0.29580575880077f);  // 500000^(-2d/128)
  float ang = (float)(t + posp[0]) * freq;
  float s, c;
  __sincosf(ang, &s, &c);
  size_t i1 = (size_t)t * 1024 + hh * 128 + d;
  float x1 = bf2f(Kb[i1]), x2 = bf2f(Kb[i1 + 64]);
  Kb[i1]      = f2bf(x1 * c - x2 * s);
  Kb[i1 + 64] = f2bf(x1 * s + x2 * c);
}

// ---------------------------------------------------------------------------
// Causal GQA flash attention. 512 thr = 8 waves x 16 q-rows, KVBLK=64,
// double-buffered counted-vmcnt staging, defer-max (T13, THR=8),
// XCD kh-locality map, in-register Q-RoPE.
// ---------------------------------------------------------------------------
__global__ __launch_bounds__(512)
void attn_kernel(const unsigned short* __restrict__ Qb,
                 const unsigned short* __restrict__ Kb,
                 const unsigned short* __restrict__ VtG,
                 unsigned short* __restrict__ Ob,
                 const int* __restrict__ posp) {
  __shared__ __align__(16) unsigned short Ks[2][64][128];
  __shared__ __align__(16) unsigned short Vt[2][128][64];
  __shared__ __align__(16) unsigned short Ps[8][16][64];
  const int tid = threadIdx.x, lane = tid & 63, w = tid >> 6;
  const int b = blockIdx.x;
  const int kh = b & 7;
  const int h  = kh * 4 + ((b >> 3) & 3);
  const int qi = b >> 5;
  const int qt = (qi < 8) ? qi : 23 - qi;
  const int q0 = qt * 128;
  const float SCALE = 0.08838834764831845f;

  const int qrow = q0 + w * 16 + (lane & 15);
  short8 aq[4];
#pragma unroll
  for (int ks = 0; ks < 4; ++ks)
    aq[ks] = *(const short8*)(Qb + (size_t)qrow * 4096 + h * 128 + ks * 32 +
                              ((lane >> 4) << 3));
  // In-register RoPE on Q: pair (d, d+64) = (aq[kp][j], aq[kp+2][j]).
  {
    const float tpos = (float)(qrow + posp[0]);
#pragma unroll
    for (int kp = 0; kp < 2; ++kp)
#pragma unroll
      for (int j = 0; j < 8; ++j) {
        const int d = kp * 32 + ((lane >> 4) << 3) + j;
        float fr = exp2f(-(float)d * 0.29580575880077f);
        float ang = tpos * fr, s, c;
        __sincosf(ang, &s, &c);
        float x0 = bf2f((unsigned short)aq[kp][j]);
        float x1 = bf2f((unsigned short)aq[kp + 2][j]);
        aq[kp][j]     = (short)f2bf(x0 * c - x1 * s);
        aq[kp + 2][j] = (short)f2bf(x0 * s + x1 * c);
      }
  }

  f32x4 o_acc[8];
#pragma unroll
  for (int n8 = 0; n8 < 8; ++n8) o_acc[n8] = (f32x4){0.f, 0.f, 0.f, 0.f};
  float mst[4], lst[4];
#pragma unroll
  for (int r = 0; r < 4; ++r) { mst[r] = -1e30f; lst[r] = 0.f; }

  auto stage = [&](int st, int bb) {
    const int s0 = st * 64;
#pragma unroll
    for (int j = 0; j < 2; ++j) {
      int sr = w * 8 + j * 4 + (lane >> 4);
      int sc = (((lane & 15) << 4) ^ ((sr & 7) << 4)) >> 1;
      gl2lds16(Kb + (size_t)(s0 + sr) * 1024 + kh * 128 + sc,
               &Ks[bb][w * 8 + j * 4][0]);
    }
#pragma unroll
    for (int j = 0; j < 2; ++j) {
      int dr = w * 16 + j * 8 + (lane >> 3);
      int sc = (((lane & 7) << 4) ^ ((dr & 7) << 4)) >> 1;
      gl2lds16(VtG + (size_t)(kh * 128 + dr) * 2048 + s0 + sc,
               &Vt[bb][w * 16 + j * 8][0]);
    }
  };

  const int ntiles = 2 * (qt + 1);
  stage(0, 0);
  for (int st = 0; st < ntiles; ++st) {
    const int cb = st & 1;
    const int s0 = st * 64;
    if (st + 1 < ntiles) {
      stage(st + 1, cb ^ 1);
      asm volatile("s_waitcnt vmcnt(4)" ::: "memory");
    } else {
      asm volatile("s_waitcnt vmcnt(0)" ::: "memory");
    }
    bar(); sfence();

    f32x4 sacc[4];
#pragma unroll
    for (int ni = 0; ni < 4; ++ni) sacc[ni] = (f32x4){0.f, 0.f, 0.f, 0.f};
#pragma unroll
    for (int ks = 0; ks < 4; ++ks) {
      const int co = ks * 64 + ((lane >> 4) << 4);
      short8 bk[4];
#pragma unroll
      for (int ni = 0; ni < 4; ++ni) {
        int kr = ni * 16 + (lane & 15);
        bk[ni] = *(const short8*)((const char*)(&Ks[cb][kr][0]) + (co ^ ((kr & 7) << 4)));
      }
#pragma unroll
      for (int ni = 0; ni < 4; ++ni)
        sacc[ni] = mfma16(aq[ks], bk[ni], sacc[ni]);
    }

    char* pb = (char*)(&Ps[w][0][0]);
#pragma unroll
    for (int r = 0; r < 4; ++r) {
      const int qr2 = q0 + w * 16 + ((lane >> 4) << 2) + r;
      float v4[4]; float vmax = -1e30f;
#pragma unroll
      for (int ni = 0; ni < 4; ++ni) {
        int scol = s0 + ni * 16 + (lane & 15);
        float x = sacc[ni][r] * SCALE;
        if (scol > qr2) x = -1e30f;
        v4[ni] = x; vmax = fmaxf(vmax, x);
      }
      vmax = fmaxf(vmax, __shfl_xor(vmax, 1));
      vmax = fmaxf(vmax, __shfl_xor(vmax, 2));
      vmax = fmaxf(vmax, __shfl_xor(vmax, 4));
      vmax = fmaxf(vmax, __shfl_xor(vmax, 8));
      float mo = mst[r];
      if (!__all(vmax <= mo + 8.0f)) {
        float mn = fmaxf(mo, vmax);
        float al = __expf(mo - mn);
        lst[r] *= al;
#pragma unroll
        for (int n8 = 0; n8 < 8; ++n8) o_acc[n8][r] *= al;
        mst[r] = mn;
      }
      float m_use = mst[r];
      float rs = 0.f;
      const int prow = ((lane >> 4) << 2) + r;
      const int pswz = ((prow >> 2) & 3) << 5;
#pragma unroll
      for (int ni = 0; ni < 4; ++ni) {
        float p = __expf(v4[ni] - m_use);
        rs += p;
        int cbyte = (ni * 16 + (lane & 15)) * 2;
        *(unsigned short*)(pb + prow * 128 + (cbyte ^ pswz)) = f2bf(p);
      }
      rs += __shfl_xor(rs, 1);
      rs += __shfl_xor(rs, 2);
      rs += __shfl_xor(rs, 4);
      rs += __shfl_xor(rs, 8);
      lst[r] += rs;
    }

#pragma unroll
    for (int ks2 = 0; ks2 < 2; ++ks2) {
      const int co = ks2 * 64 + ((lane >> 4) << 4);
      const int pr = lane & 15;
      short8 pa = *(const short8*)(pb + pr * 128 + (co ^ (((pr >> 2) & 3) << 5)));
#pragma unroll
      for (int n8 = 0; n8 < 8; ++n8) {
        int vr = n8 * 16 + (lane & 15);
        short8 bv = *(const short8*)((const char*)(&Vt[cb][vr][0]) + (co ^ ((vr & 7) << 4)));
        o_acc[n8] = mfma16(pa, bv, o_acc[n8]);
      }
    }
    sfence(); bar(); sfence();
  }

#pragma unroll
  for (int r = 0; r < 4; ++r) {
    float inv = 1.0f / lst[r];
    int row = q0 + w * 16 + ((lane >> 4) << 2) + r;
#pragma unroll
    for (int n8 = 0; n8 < 8; ++n8)
      Ob[(size_t)row * 4096 + h * 128 + n8 * 16 + (lane & 15)] =
          f2bf(o_acc[n8][r] * inv);
  }
}

// ---------------------------------------------------------------------------
// GEMM 2 (m97 structure): O projection, fp32 out. XCD 8x8 rectangle map.
// ---------------------------------------------------------------------------
__global__ __launch_bounds__(256, 2)
void gemm_out_bf16(const unsigned short* __restrict__ Ab,
                   const unsigned short* __restrict__ Wob,
                   float* __restrict__ Cout) {
  const int K = 4096;
  __shared__ __align__(16) unsigned short As[128][64];
  __shared__ __align__(16) unsigned short Bs[128][64];
  const int tid = threadIdx.x, lane = tid & 63, wid = tid >> 6;
  const int bid = blockIdx.x;                 // 0..511
  const int xcd = bid & 7, idx = bid >> 3;    // idx 0..63
  const int m0 = ((xcd & 1) * 8 + (idx & 7)) * 128;
  const int n0 = ((xcd >> 1) * 8 + (idx >> 3)) * 128;
  const unsigned short* Asrc = Ab + (size_t)m0 * K;
  const unsigned short* Bsrc = Wob + (size_t)n0 * K;

  f32x4 acc[4][4];
#pragma unroll
  for (int i = 0; i < 4; ++i)
#pragma unroll
    for (int j = 0; j < 4; ++j) acc[i][j] = (f32x4){0.f, 0.f, 0.f, 0.f};

  const int wm = (wid >> 1) * 64, wn = (wid & 1) * 64;
  const int srow = wid * 32 + (lane >> 3);
  const int scol = (lane & 7) * 8;

  for (int k0 = 0; k0 < K; k0 += 64) {
#pragma unroll
    for (int i = 0; i < 4; ++i) {
      gl2lds16(Asrc + (size_t)(srow + i * 8) * K + k0 + scol, &As[wid * 32 + i * 8][0]);
      gl2lds16(Bsrc + (size_t)(srow + i * 8) * K + k0 + scol, &Bs[wid * 32 + i * 8][0]);
    }
    __syncthreads();
#pragma unroll
    for (int ks = 0; ks < 2; ++ks) {
      short8 af[4], bfr[4];
      const int co = ks * 64 + ((lane >> 4) << 4);
#pragma unroll
      for (int i = 0; i < 4; ++i) {
        af[i]  = *(const short8*)((const char*)(&As[wm + i * 16 + (lane & 15)][0]) + co);
        bfr[i] = *(const short8*)((const char*)(&Bs[wn + i * 16 + (lane & 15)][0]) + co);
      }
#pragma unroll
      for (int i = 0; i < 4; ++i)
#pragma unroll
        for (int j = 0; j < 4; ++j)
          acc[i][j] = mfma16(af[i], bfr[j], acc[i][j]);
    }
    __syncthreads();
  }

#pragma unroll
  for (int i = 0; i < 4; ++i) {
    int rb = m0 + wm + i * 16 + ((lane >> 4) << 2);
#pragma unroll
    for (int j = 0; j < 4; ++j) {
      int cb = n0 + wn + j * 16 + (lane & 15);
#pragma unroll
      for (int r = 0; r < 4; ++r)
        Cout[(size_t)(rb + r) * 4096 + cb] = acc[i][j][r];
    }
  }
}

extern "C" void kernel_launch(void* const* d_in, const int* in_sizes, int n_in,
                              void* d_out, int out_size, void* d_ws, size_t ws_size,
                              hipStream_t stream) {
  const float* hs = (const float*)d_in[0];
  const float* Wq = (const float*)d_in[1];
  const float* Wk = (const float*)d_in[2];
  const float* Wv = (const float*)d_in[3];
  const float* Wo = (const float*)d_in[4];
  const int* pos = (const int*)d_in[7];

  unsigned short* hsb = (unsigned short*)d_ws;              // 8M
  unsigned short* Wqb = hsb + (size_t)8  * 1024 * 1024;     // 16M
  unsigned short* Wkb = Wqb + (size_t)16 * 1024 * 1024;     // 4M
  unsigned short* Wvb = Wkb + (size_t)4  * 1024 * 1024;     // 4M
  unsigned short* Wob = Wvb + (size_t)4  * 1024 * 1024;     // 16M
  unsigned short* Qb  = Wob + (size_t)16 * 1024 * 1024;     // 8M
  unsigned short* Kb  = Qb  + (size_t)8  * 1024 * 1024;     // 2M
  unsigned short* VtG = Kb  + (size_t)2  * 1024 * 1024;     // 2M
  unsigned short* Ob  = VtG + (size_t)2  * 1024 * 1024;     // 8M
  float* out = (float*)d_out;

  cvt4_kernel<<<dim3(2048), 256, 0, stream>>>(
      hs, Wq, Wk, Wv, hsb, Wqb, Wkb, Wvb,
      2 * 1024 * 1024, 4 * 1024 * 1024, 1 * 1024 * 1024, 1 * 1024 * 1024);

  gemm_qkv_8ph<<<dim3(256), 512, 0, stream>>>(hsb, Wqb, Wkb, Wvb, Qb, Kb, VtG,
                                              Wo, Wob);

  const int kpairs = 2048 * 8 * 64;
  rope_k_kernel<<<dim3((kpairs + 255) / 256), 256, 0, stream>>>(Kb, pos);

  attn_kernel<<<dim3(512), 512, 0, stream>>>(Qb, Kb, VtG, Ob, pos);
  gemm_out_bf16<<<dim3(512), 256, 0, stream>>>(Ob, Wob, out);
}

// Round 23
// 337.452 us; speedup vs baseline: 1.0101x; 1.0015x over previous
//
#include <hip/hip_runtime.h>

// Fused GQA prefill: cvt4(fp32->bf16: hs,Wq,Wk,Wv) -> QKV proj (8-phase 256^2,
// V transposed epilogue; 64 extra blocks convert Wo on otherwise-idle CUs) ->
// RoPE(K only, vectorized; Q roped in-register in attn) -> causal flash attn
// (8-wave, KVBLK=64 dbuf, counted vmcnt, defer-max, XCD kh-locality) ->
// O proj (m97 128^2, XCD 8x8 rectangle map).
// B=1, T=2048, HID=4096, H=32, HKV=8, DH=128, pos=0.

#define DEVI __device__ __forceinline__

typedef __attribute__((ext_vector_type(8))) short short8;
typedef __attribute__((ext_vector_type(4))) float f32x4;

DEVI unsigned short f2bf(float f) {
  union { float f; unsigned u; } x; x.f = f;
  unsigned r = x.u + 0x7FFFu + ((x.u >> 16) & 1u);
  return (unsigned short)(r >> 16);
}
DEVI float bf2f(unsigned short h) {
  union { unsigned u; float f; } x; x.u = ((unsigned)h) << 16;
  return x.f;
}
DEVI f32x4 mfma16(short8 a, short8 b, f32x4 c) {
  return __builtin_amdgcn_mfma_f32_16x16x32_bf16(a, b, c, 0, 0, 0);
}
DEVI void gl2lds16(const unsigned short* g, unsigned short* l) {
  __builtin_amdgcn_global_load_lds(
      (const __attribute__((address_space(1))) unsigned int*)g,
      (__attribute__((address_space(3))) unsigned int*)l, 16, 0, 0);
}
DEVI void bar() { __builtin_amdgcn_s_barrier(); }
DEVI void sfence() { __builtin_amdgcn_sched_barrier(0); }

DEVI void cvt_region(const float* __restrict__ src,
                     unsigned short* __restrict__ dst, int n4, int start,
                     int stride) {
  for (int i = start; i < n4; i += stride) {
    float4 v = ((const float4*)src)[i];
    ushort4 h;
    h.x = f2bf(v.x); h.y = f2bf(v.y); h.z = f2bf(v.z); h.w = f2bf(v.w);
    ((ushort4*)dst)[i] = h;
  }
}

// ---------------------------------------------------------------------------
// One-launch fp32 -> bf16 conversion of hs, Wq, Wk, Wv (Wo handled in qkv).
// ---------------------------------------------------------------------------
__global__ __launch_bounds__(256)
void cvt4_kernel(const float* __restrict__ s0, const float* __restrict__ s1,
                 const float* __restrict__ s2, const float* __restrict__ s3,
                 unsigned short* __restrict__ d0, unsigned short* __restrict__ d1,
                 unsigned short* __restrict__ d2, unsigned short* __restrict__ d3,
                 int n0, int n1, int n2, int n3) {
  const int start = blockIdx.x * 256 + threadIdx.x;
  const int stride = gridDim.x * 256;
  cvt_region(s0, d0, n0, start, stride);
  cvt_region(s1, d1, n1, start, stride);
  cvt_region(s2, d2, n2, start, stride);
  cvt_region(s3, d3, n3, start, stride);
}

// ---------------------------------------------------------------------------
// GEMM 1: QKV projection, 8-phase 256x256 template, 1D grid of 256 blocks:
// bid<192 = GEMM (bx=bid%24, by=bid/24); bid>=192 = 64 converter blocks that
// stream Wo fp32->bf16 on the CUs the GEMM leaves idle. V-region GEMM blocks
// write output TRANSPOSED into VtG.
// ---------------------------------------------------------------------------
__global__ __launch_bounds__(512, 2)
void gemm_qkv_8ph(const unsigned short* __restrict__ hsb,
                  const unsigned short* __restrict__ Wqb,
                  const unsigned short* __restrict__ Wkb,
                  const unsigned short* __restrict__ Wvb,
                  unsigned short* __restrict__ Qb,
                  unsigned short* __restrict__ Kb,
                  unsigned short* __restrict__ VtG,
                  const float* __restrict__ Wo,
                  unsigned short* __restrict__ Wob) {
  const int K = 4096;
  const int NT = 64;
  __shared__ __align__(16) unsigned short Ls[2][2][2][256][32]; // 128 KiB
  const int tid = threadIdx.x, lane = tid & 63, w = tid >> 6;
  const int bid = blockIdx.x;

  if (bid >= 192) {
    const int start = (bid - 192) * 512 + tid;
    cvt_region(Wo, Wob, 4 * 1024 * 1024, start, 64 * 512);
    return;
  }

  const int wr = w >> 2, wc = w & 3;
  const int m0 = (bid / 24) * 256;
  const int n0g = (bid % 24) * 256;

  const unsigned short* Bsrc; unsigned short* outp; int ldo, oc; bool isv = false;
  if (n0g < 4096)      { Bsrc = Wqb + (size_t)n0g * K;          outp = Qb; ldo = 4096; oc = n0g; }
  else if (n0g < 5120) { Bsrc = Wkb + (size_t)(n0g - 4096) * K; outp = Kb; ldo = 1024; oc = n0g - 4096; }
  else                 { Bsrc = Wvb + (size_t)(n0g - 5120) * K; outp = VtG; ldo = 0; oc = n0g - 5120; isv = true; }
  const unsigned short* Asrc = hsb + (size_t)m0 * K;

  auto stageU = [&](const unsigned short* src, int ab, int kh, int tt, int bb) {
#pragma unroll
    for (int j = 0; j < 2; ++j) {
      const int seg = j * 8 + w;
      const int row = seg * 16 + (lane >> 2);
      const int cs  = (lane & 3) ^ ((row >> 1) & 3);
      gl2lds16(src + (size_t)row * K + tt * 64 + kh * 32 + cs * 8,
               &Ls[bb][ab][kh][seg * 16][0]);
    }
  };
  auto ldA = [&](int bb, int kh, int fm) -> short8 {
    const int ra = wr * 128 + fm * 16 + (lane & 15);
    const int cs = (lane >> 4) ^ ((ra >> 1) & 3);
    return *(const short8*)&Ls[bb][0][kh][ra][cs * 8];
  };
  auto ldB = [&](int bb, int kh, int fn) -> short8 {
    const int rb = wc * 64 + fn * 16 + (lane & 15);
    const int cs = (lane >> 4) ^ ((rb >> 1) & 3);
    return *(const short8*)&Ls[bb][1][kh][rb][cs * 8];
  };

  f32x4 acc[8][4];
#pragma unroll
  for (int i = 0; i < 8; ++i)
#pragma unroll
    for (int j = 0; j < 4; ++j) acc[i][j] = (f32x4){0.f, 0.f, 0.f, 0.f};

  stageU(Asrc, 0, 0, 0, 0);
  stageU(Asrc, 0, 1, 0, 0);
  stageU(Bsrc, 1, 0, 0, 0);
  stageU(Bsrc, 1, 1, 0, 0);
  stageU(Bsrc, 1, 0, 1, 1);
  stageU(Asrc, 0, 0, 1, 1);
  stageU(Bsrc, 1, 1, 1, 1);
  asm volatile("s_waitcnt vmcnt(6)" ::: "memory");
  bar();
  sfence();

  short8 af[4], bfr[4];
  for (int t = 0; t < NT; ++t) {
    const int bb = t & 1, nb = bb ^ 1;
    // P1: (kh0, mq0); stage A(t+1)-kh1 -> nb
#pragma unroll
    for (int i = 0; i < 4; ++i) af[i] = ldA(bb, 0, i);
#pragma unroll
    for (int i = 0; i < 4; ++i) bfr[i] = ldB(bb, 0, i);
    if (t + 1 < NT) stageU(Asrc, 0, 1, t + 1, nb);
    bar();
    __builtin_amdgcn_s_setprio(1);
#pragma unroll
    for (int i = 0; i < 4; ++i)
#pragma unroll
      for (int j = 0; j < 4; ++j) acc[i][j] = mfma16(af[i], bfr[j], acc[i][j]);
    __builtin_amdgcn_s_setprio(0);
    sfence(); bar(); sfence();
    // P2: (kh0, mq1); stage B(t+2)-kh0 -> bb
#pragma unroll
    for (int i = 0; i < 4; ++i) af[i] = ldA(bb, 0, 4 + i);
    if (t + 2 < NT) stageU(Bsrc, 1, 0, t + 2, bb);
    bar();
    __builtin_amdgcn_s_setprio(1);
#pragma unroll
    for (int i = 0; i < 4; ++i)
#pragma unroll
      for (int j = 0; j < 4; ++j) acc[4 + i][j] = mfma16(af[i], bfr[j], acc[4 + i][j]);
    __builtin_amdgcn_s_setprio(0);
    sfence(); bar(); sfence();
    // P3: (kh1, mq0); stage A(t+2)-kh0 -> bb
#pragma unroll
    for (int i = 0; i < 4; ++i) af[i] = ldA(bb, 1, i);
#pragma unroll
    for (int i = 0; i < 4; ++i) bfr[i] = ldB(bb, 1, i);
    if (t + 2 < NT) stageU(Asrc, 0, 0, t + 2, bb);
    bar();
    __builtin_amdgcn_s_setprio(1);
#pragma unroll
    for (int i = 0; i < 4; ++i)
#pragma unroll
      for (int j = 0; j < 4; ++j) acc[i][j] = mfma16(af[i], bfr[j], acc[i][j]);
    __builtin_amdgcn_s_setprio(0);
    sfence(); bar(); sfence();
    // P4: (kh1, mq1); stage B(t+2)-kh1 -> bb; counted vmcnt
#pragma unroll
    for (int i = 0; i < 4; ++i) af[i] = ldA(bb, 1, 4 + i);
    if (t + 2 < NT) stageU(Bsrc, 1, 1, t + 2, bb);
    bar();
    __builtin_amdgcn_s_setprio(1);
#pragma unroll
    for (int i = 0; i < 4; ++i)
#pragma unroll
      for (int j = 0; j < 4; ++j) acc[4 + i][j] = mfma16(af[i], bfr[j], acc[4 + i][j]);
    __builtin_amdgcn_s_setprio(0);
    if (t < NT - 2) asm volatile("s_waitcnt vmcnt(6)" ::: "memory");
    else            asm volatile("s_waitcnt vmcnt(0)" ::: "memory");
    sfence(); bar(); sfence();
  }

  if (isv) {
#pragma unroll
    for (int fm = 0; fm < 8; ++fm) {
      const int rb0 = m0 + wr * 128 + fm * 16 + ((lane >> 4) << 2);
#pragma unroll
      for (int fn = 0; fn < 4; ++fn) {
        const int cb = oc + wc * 64 + fn * 16 + (lane & 15);
        ushort4 v;
        v.x = f2bf(acc[fm][fn][0]); v.y = f2bf(acc[fm][fn][1]);
        v.z = f2bf(acc[fm][fn][2]); v.w = f2bf(acc[fm][fn][3]);
        *(ushort4*)(VtG + (size_t)cb * 2048 + rb0) = v;
      }
    }
  } else {
#pragma unroll
    for (int fm = 0; fm < 8; ++fm) {
      const int rb0 = m0 + wr * 128 + fm * 16 + ((lane >> 4) << 2);
#pragma unroll
      for (int fn = 0; fn < 4; ++fn) {
        const int cb = oc + wc * 64 + fn * 16 + (lane & 15);
#pragma unroll
        for (int r = 0; r < 4; ++r)
          outp[(size_t)(rb0 + r) * ldo + cb] = f2bf(acc[fm][fn][r]);
      }
    }
  }
}

// ---------------------------------------------------------------------------
// RoPE in place on bf16 K only, vectorized: each thread rotates 4 consecutive
// d's (two ushort4 loads/stores). Q is roped in-register inside attn.
// ---------------------------------------------------------------------------
__global__ __launch_bounds__(256)
void rope_k_kernel(unsigned short* __restrict__ Kb,
                   const int* __restrict__ posp) {
  const int NV = 2048 * 8 * 16;  // vec items: 16 groups of 4 pairs per (t,hh)
  int idx = blockIdx.x * 256 + threadIdx.x;
  if (idx >= NV) return;
  const int t = idx >> 7;
  const int rem = idx & 127;
  const int hh = rem >> 4;
  const int d0 = (rem & 15) << 2;
  const float tpos = (float)(t + posp[0]);
  size_t base = (size_t)t * 1024 + hh * 128 + d0;
  ushort4 lo = *(ushort4*)(Kb + base);
  ushort4 hi = *(ushort4*)(Kb + base + 64);
  unsigned short* lp = (unsigned short*)&lo;
  unsigned short* hp = (unsigned short*)&hi;
#pragma unroll
  for (int j = 0; j < 4; ++j) {
    float freq = exp2f(-(float)(d0 + j) * 0.29580575880077f);  // 500000^(-2d/128)
    float ang = tpos * freq, s, c;
    __sincosf(ang, &s, &c);
    float x1 = bf2f(lp[j]), x2 = bf2f(hp[j]);
    lp[j] = f2bf(x1 * c - x2 * s);
    hp[j] = f2bf(x1 * s + x2 * c);
  }
  *(ushort4*)(Kb + base) = lo;
  *(ushort4*)(Kb + base + 64) = hi;
}

// ---------------------------------------------------------------------------
// Causal GQA flash attention. 512 thr = 8 waves x 16 q-rows, KVBLK=64,
// double-buffered counted-vmcnt staging, defer-max (T13, THR=8),
// XCD kh-locality map, in-register Q-RoPE.
// ---------------------------------------------------------------------------
__global__ __launch_bounds__(512)
void attn_kernel(const unsigned short* __restrict__ Qb,
                 const unsigned short* __restrict__ Kb,
                 const unsigned short* __restrict__ VtG,
                 unsigned short* __restrict__ Ob,
                 const int* __restrict__ posp) {
  __shared__ __align__(16) unsigned short Ks[2][64][128];
  __shared__ __align__(16) unsigned short Vt[2][128][64];
  __shared__ __align__(16) unsigned short Ps[8][16][64];
  const int tid = threadIdx.x, lane = tid & 63, w = tid >> 6;
  const int b = blockIdx.x;
  const int kh = b & 7;
  const int h  = kh * 4 + ((b >> 3) & 3);
  const int qi = b >> 5;
  const int qt = (qi < 8) ? qi : 23 - qi;
  const int q0 = qt * 128;
  const float SCALE = 0.08838834764831845f;

  const int qrow = q0 + w * 16 + (lane & 15);
  short8 aq[4];
#pragma unroll
  for (int ks = 0; ks < 4; ++ks)
    aq[ks] = *(const short8*)(Qb + (size_t)qrow * 4096 + h * 128 + ks * 32 +
                              ((lane >> 4) << 3));
  // In-register RoPE on Q: pair (d, d+64) = (aq[kp][j], aq[kp+2][j]).
  {
    const float tpos = (float)(qrow + posp[0]);
#pragma unroll
    for (int kp = 0; kp < 2; ++kp)
#pragma unroll
      for (int j = 0; j < 8; ++j) {
        const int d = kp * 32 + ((lane >> 4) << 3) + j;
        float fr = exp2f(-(float)d * 0.29580575880077f);
        float ang = tpos * fr, s, c;
        __sincosf(ang, &s, &c);
        float x0 = bf2f((unsigned short)aq[kp][j]);
        float x1 = bf2f((unsigned short)aq[kp + 2][j]);
        aq[kp][j]     = (short)f2bf(x0 * c - x1 * s);
        aq[kp + 2][j] = (short)f2bf(x0 * s + x1 * c);
      }
  }

  f32x4 o_acc[8];
#pragma unroll
  for (int n8 = 0; n8 < 8; ++n8) o_acc[n8] = (f32x4){0.f, 0.f, 0.f, 0.f};
  float mst[4], lst[4];
#pragma unroll
  for (int r = 0; r < 4; ++r) { mst[r] = -1e30f; lst[r] = 0.f; }

  auto stage = [&](int st, int bb) {
    const int s0 = st * 64;
#pragma unroll
    for (int j = 0; j < 2; ++j) {
      int sr = w * 8 + j * 4 + (lane >> 4);
      int sc = (((lane & 15) << 4) ^ ((sr & 7) << 4)) >> 1;
      gl2lds16(Kb + (size_t)(s0 + sr) * 1024 + kh * 128 + sc,
               &Ks[bb][w * 8 + j * 4][0]);
    }
#pragma unroll
    for (int j = 0; j < 2; ++j) {
      int dr = w * 16 + j * 8 + (lane >> 3);
      int sc = (((lane & 7) << 4) ^ ((dr & 7) << 4)) >> 1;
      gl2lds16(VtG + (size_t)(kh * 128 + dr) * 2048 + s0 + sc,
               &Vt[bb][w * 16 + j * 8][0]);
    }
  };

  const int ntiles = 2 * (qt + 1);
  stage(0, 0);
  for (int st = 0; st < ntiles; ++st) {
    const int cb = st & 1;
    const int s0 = st * 64;
    if (st + 1 < ntiles) {
      stage(st + 1, cb ^ 1);
      asm volatile("s_waitcnt vmcnt(4)" ::: "memory");
    } else {
      asm volatile("s_waitcnt vmcnt(0)" ::: "memory");
    }
    bar(); sfence();

    f32x4 sacc[4];
#pragma unroll
    for (int ni = 0; ni < 4; ++ni) sacc[ni] = (f32x4){0.f, 0.f, 0.f, 0.f};
#pragma unroll
    for (int ks = 0; ks < 4; ++ks) {
      const int co = ks * 64 + ((lane >> 4) << 4);
      short8 bk[4];
#pragma unroll
      for (int ni = 0; ni < 4; ++ni) {
        int kr = ni * 16 + (lane & 15);
        bk[ni] = *(const short8*)((const char*)(&Ks[cb][kr][0]) + (co ^ ((kr & 7) << 4)));
      }
#pragma unroll
      for (int ni = 0; ni < 4; ++ni)
        sacc[ni] = mfma16(aq[ks], bk[ni], sacc[ni]);
    }

    char* pb = (char*)(&Ps[w][0][0]);
#pragma unroll
    for (int r = 0; r < 4; ++r) {
      const int qr2 = q0 + w * 16 + ((lane >> 4) << 2) + r;
      float v4[4]; float vmax = -1e30f;
#pragma unroll
      for (int ni = 0; ni < 4; ++ni) {
        int scol = s0 + ni * 16 + (lane & 15);
        float x = sacc[ni][r] * SCALE;
        if (scol > qr2) x = -1e30f;
        v4[ni] = x; vmax = fmaxf(vmax, x);
      }
      vmax = fmaxf(vmax, __shfl_xor(vmax, 1));
      vmax = fmaxf(vmax, __shfl_xor(vmax, 2));
      vmax = fmaxf(vmax, __shfl_xor(vmax, 4));
      vmax = fmaxf(vmax, __shfl_xor(vmax, 8));
      float mo = mst[r];
      if (!__all(vmax <= mo + 8.0f)) {
        float mn = fmaxf(mo, vmax);
        float al = __expf(mo - mn);
        lst[r] *= al;
#pragma unroll
        for (int n8 = 0; n8 < 8; ++n8) o_acc[n8][r] *= al;
        mst[r] = mn;
      }
      float m_use = mst[r];
      float rs = 0.f;
      const int prow = ((lane >> 4) << 2) + r;
      const int pswz = ((prow >> 2) & 3) << 5;
#pragma unroll
      for (int ni = 0; ni < 4; ++ni) {
        float p = __expf(v4[ni] - m_use);
        rs += p;
        int cbyte = (ni * 16 + (lane & 15)) * 2;
        *(unsigned short*)(pb + prow * 128 + (cbyte ^ pswz)) = f2bf(p);
      }
      rs += __shfl_xor(rs, 1);
      rs += __shfl_xor(rs, 2);
      rs += __shfl_xor(rs, 4);
      rs += __shfl_xor(rs, 8);
      lst[r] += rs;
    }

#pragma unroll
    for (int ks2 = 0; ks2 < 2; ++ks2) {
      const int co = ks2 * 64 + ((lane >> 4) << 4);
      const int pr = lane & 15;
      short8 pa = *(const short8*)(pb + pr * 128 + (co ^ (((pr >> 2) & 3) << 5)));
#pragma unroll
      for (int n8 = 0; n8 < 8; ++n8) {
        int vr = n8 * 16 + (lane & 15);
        short8 bv = *(const short8*)((const char*)(&Vt[cb][vr][0]) + (co ^ ((vr & 7) << 4)));
        o_acc[n8] = mfma16(pa, bv, o_acc[n8]);
      }
    }
    sfence(); bar(); sfence();
  }

#pragma unroll
  for (int r = 0; r < 4; ++r) {
    float inv = 1.0f / lst[r];
    int row = q0 + w * 16 + ((lane >> 4) << 2) + r;
#pragma unroll
    for (int n8 = 0; n8 < 8; ++n8)
      Ob[(size_t)row * 4096 + h * 128 + n8 * 16 + (lane & 15)] =
          f2bf(o_acc[n8][r] * inv);
  }
}

// ---------------------------------------------------------------------------
// GEMM 2 (m97 structure): O projection, fp32 out. XCD 8x8 rectangle map.
// ---------------------------------------------------------------------------
__global__ __launch_bounds__(256, 2)
void gemm_out_bf16(const unsigned short* __restrict__ Ab,
                   const unsigned short* __restrict__ Wob,
                   float* __restrict__ Cout) {
  const int K = 4096;
  __shared__ __align__(16) unsigned short As[128][64];
  __shared__ __align__(16) unsigned short Bs[128][64];
  const int tid = threadIdx.x, lane = tid & 63, wid = tid >> 6;
  const int bid = blockIdx.x;                 // 0..511
  const int xcd = bid & 7, idx = bid >> 3;    // idx 0..63
  const int m0 = ((xcd & 1) * 8 + (idx & 7)) * 128;
  const int n0 = ((xcd >> 1) * 8 + (idx >> 3)) * 128;
  const unsigned short* Asrc = Ab + (size_t)m0 * K;
  const unsigned short* Bsrc = Wob + (size_t)n0 * K;

  f32x4 acc[4][4];
#pragma unroll
  for (int i = 0; i < 4; ++i)
#pragma unroll
    for (int j = 0; j < 4; ++j) acc[i][j] = (f32x4){0.f, 0.f, 0.f, 0.f};

  const int wm = (wid >> 1) * 64, wn = (wid & 1) * 64;
  const int srow = wid * 32 + (lane >> 3);
  const int scol = (lane & 7) * 8;

  for (int k0 = 0; k0 < K; k0 += 64) {
#pragma unroll
    for (int i = 0; i < 4; ++i) {
      gl2lds16(Asrc + (size_t)(srow + i * 8) * K + k0 + scol, &As[wid * 32 + i * 8][0]);
      gl2lds16(Bsrc + (size_t)(srow + i * 8) * K + k0 + scol, &Bs[wid * 32 + i * 8][0]);
    }
    __syncthreads();
#pragma unroll
    for (int ks = 0; ks < 2; ++ks) {
      short8 af[4], bfr[4];
      const int co = ks * 64 + ((lane >> 4) << 4);
#pragma unroll
      for (int i = 0; i < 4; ++i) {
        af[i]  = *(const short8*)((const char*)(&As[wm + i * 16 + (lane & 15)][0]) + co);
        bfr[i] = *(const short8*)((const char*)(&Bs[wn + i * 16 + (lane & 15)][0]) + co);
      }
#pragma unroll
      for (int i = 0; i < 4; ++i)
#pragma unroll
        for (int j = 0; j < 4; ++j)
          acc[i][j] = mfma16(af[i], bfr[j], acc[i][j]);
    }
    __syncthreads();
  }

#pragma unroll
  for (int i = 0; i < 4; ++i) {
    int rb = m0 + wm + i * 16 + ((lane >> 4) << 2);
#pragma unroll
    for (int j = 0; j < 4; ++j) {
      int cb = n0 + wn + j * 16 + (lane & 15);
#pragma unroll
      for (int r = 0; r < 4; ++r)
        Cout[(size_t)(rb + r) * 4096 + cb] = acc[i][j][r];
    }
  }
}

extern "C" void kernel_launch(void* const* d_in, const int* in_sizes, int n_in,
                              void* d_out, int out_size, void* d_ws, size_t ws_size,
                              hipStream_t stream) {
  const float* hs = (const float*)d_in[0];
  const float* Wq = (const float*)d_in[1];
  const float* Wk = (const float*)d_in[2];
  const float* Wv = (const float*)d_in[3];
  const float* Wo = (const float*)d_in[4];
  const int* pos = (const int*)d_in[7];

  unsigned short* hsb = (unsigned short*)d_ws;              // 8M
  unsigned short* Wqb = hsb + (size_t)8  * 1024 * 1024;     // 16M
  unsigned short* Wkb = Wqb + (size_t)16 * 1024 * 1024;     // 4M
  unsigned short* Wvb = Wkb + (size_t)4  * 1024 * 1024;     // 4M
  unsigned short* Wob = Wvb + (size_t)4  * 1024 * 1024;     // 16M
  unsigned short* Qb  = Wob + (size_t)16 * 1024 * 1024;     // 8M
  unsigned short* Kb  = Qb  + (size_t)8  * 1024 * 1024;     // 2M
  unsigned short* VtG = Kb  + (size_t)2  * 1024 * 1024;     // 2M
  unsigned short* Ob  = VtG + (size_t)2  * 1024 * 1024;     // 8M
  float* out = (float*)d_out;

  cvt4_kernel<<<dim3(2048), 256, 0, stream>>>(
      hs, Wq, Wk, Wv, hsb, Wqb, Wkb, Wvb,
      2 * 1024 * 1024, 4 * 1024 * 1024, 1 * 1024 * 1024, 1 * 1024 * 1024);

  gemm_qkv_8ph<<<dim3(256), 512, 0, stream>>>(hsb, Wqb, Wkb, Wvb, Qb, Kb, VtG,
                                              Wo, Wob);

  const int nvec = 2048 * 8 * 16;
  rope_k_kernel<<<dim3((nvec + 255) / 256), 256, 0, stream>>>(Kb, pos);

  attn_kernel<<<dim3(512), 512, 0, stream>>>(Qb, Kb, VtG, Ob, pos);
  gemm_out_bf16<<<dim3(512), 256, 0, stream>>>(Ob, Wob, out);
}